// Round 1
// 226.679 us; speedup vs baseline: 1.2221x; 1.2221x over previous
//
#include <hip/hip_runtime.h>
#include <stdint.h>

#define N_NODES 50000
#define HC 256
#define IN_C 128
#define SCAN_B 196          // ceil(50000/256)

typedef __bf16 v8bf __attribute__((ext_vector_type(8)));
typedef float  v4f  __attribute__((ext_vector_type(4)));

__device__ __forceinline__ uint16_t f2bf(float f) {
    union { float f; uint32_t i; } c; c.f = f;
    uint32_t x = c.i;
    uint32_t r = x + 0x7fffu + ((x >> 16) & 1u);
    return (uint16_t)(r >> 16);
}
__device__ __forceinline__ uint16_t f2h(float f) {
    union { _Float16 h; uint16_t u; } c;
    c.h = (_Float16)f;
    return c.u;
}
__device__ __forceinline__ void ld4h(uint2 u, float& f0, float& f1, float& f2, float& f3) {
    union { uint32_t i; _Float16 h[2]; } c;
    c.i = u.x; f0 = (float)c.h[0]; f1 = (float)c.h[1];
    c.i = u.y; f2 = (float)c.h[0]; f3 = (float)c.h[1];
}
__device__ __forceinline__ void h8(uint4 u, float* f) {
    union { uint32_t i; _Float16 h[2]; } c;
    c.i = u.x; f[0] = (float)c.h[0]; f[1] = (float)c.h[1];
    c.i = u.y; f[2] = (float)c.h[0]; f[3] = (float)c.h[1];
    c.i = u.z; f[4] = (float)c.h[0]; f[5] = (float)c.h[1];
    c.i = u.w; f[6] = (float)c.h[0]; f[7] = (float)c.h[1];
}

// ---- W fp32 [128][256] -> Wt bf16 [256][128] ----
__global__ void k_wt(const float* __restrict__ W, uint16_t* __restrict__ Wt) {
    int idx = blockIdx.x * 256 + threadIdx.x;
    int k = idx >> 8;
    int c = idx & 255;
    Wt[c * IN_C + k] = f2bf(W[idx]);
}

// ---- fused: xw = x@W (MFMA), fp16 payload write (coalesced via LDS),
// ----        + a_src/a_dst logits computed in the write-out pass ----
// block = 256 threads = 4 waves; 16 nodes x 256 cols per block.
__global__ __launch_bounds__(256) void k_gemm_fused(const float* __restrict__ x,
                                                    const uint16_t* __restrict__ Wt,
                                                    const float* __restrict__ att_src,
                                                    const float* __restrict__ att_dst,
                                                    uint16_t* __restrict__ xwh,
                                                    float* __restrict__ a_src,
                                                    float* __restrict__ a_dst) {
    __shared__ uint16_t lx[16 * 136];   // bf16 x tile, row stride 136 (pad 8)
    __shared__ uint16_t lc[16 * 272];   // fp16 c tile, row stride 272 (pad 16)
    int t  = threadIdx.x;
    int nb = blockIdx.x * 16;

    // ---- stage x -> LDS bf16 (each thread: 8 floats, coalesced) ----
    {
        int row = t >> 4, c8 = (t & 15) * 8;
        const float4* p = (const float4*)(x + (size_t)(nb + row) * IN_C + c8);
        float4 p0 = p[0], p1 = p[1];
        v8bf a;
        a[0] = (__bf16)p0.x; a[1] = (__bf16)p0.y; a[2] = (__bf16)p0.z; a[3] = (__bf16)p0.w;
        a[4] = (__bf16)p1.x; a[5] = (__bf16)p1.y; a[6] = (__bf16)p1.z; a[7] = (__bf16)p1.w;
        *(v8bf*)(lx + row * 136 + c8) = a;
    }
    __syncthreads();

    // ---- MFMA: wave w owns cols [w*64, w*64+64) of all 16 nodes ----
    int w = t >> 6, lane = t & 63;
    int m = lane & 15, g = lane >> 4;
    v4f acc[4];
#pragma unroll
    for (int ct = 0; ct < 4; ++ct) acc[ct] = (v4f){0.f, 0.f, 0.f, 0.f};
    const uint16_t* lxp = lx + m * 136 + g * 8;
    const uint16_t* wp  = Wt + (size_t)(w * 64 + m) * IN_C + g * 8;
#pragma unroll
    for (int s = 0; s < 4; ++s) {
        v8bf a = *(const v8bf*)(lxp + s * 32);
#pragma unroll
        for (int ct = 0; ct < 4; ++ct) {
            v8bf b = *(const v8bf*)(wp + (size_t)ct * 16 * IN_C + s * 32);
            acc[ct] = __builtin_amdgcn_mfma_f32_16x16x32_bf16(a, b, acc[ct], 0, 0, 0);
        }
    }

    // ---- acc -> LDS fp16; XOR-swizzle ct-bits with g so the 4 lane-groups
    // ---- hit disjoint 8-bank windows (conflict-free b16 writes) ----
#pragma unroll
    for (int ct = 0; ct < 4; ++ct) {
        int cols = w * 64 + ((ct ^ g) << 4) + m;   // storage col = logical ^ (g<<4)
#pragma unroll
        for (int r = 0; r < 4; ++r) {
            lc[(g * 4 + r) * 272 + cols] = f2h(acc[ct][r]);
        }
    }
    __syncthreads();

    // ---- coalesced write-out + fused logits ----
    {
        int row = t >> 4;          // 0..15 ; row>>2 == wave id => shfl stays in-wave
        int c   = t & 15;          // logical 8-col group (of 32 per row)
        int gg  = row >> 2;
        int sc0 = c ^ (gg << 1);             // swizzled group for logical c
        int sc1 = sc0 + 16;                  // logical c+16 (bit4 untouched by swizzle)
        const uint16_t* lr = lc + row * 272;
        uint4 u0 = *(const uint4*)(lr + sc0 * 8);
        uint4 u1 = *(const uint4*)(lr + sc1 * 8);
        size_t gb = (size_t)(nb + row) * HC + c * 8;
        *(uint4*)(xwh + gb)       = u0;      // 16 threads -> 256B contiguous
        *(uint4*)(xwh + gb + 128) = u1;

        float f0[8], f1[8];
        h8(u0, f0);
        h8(u1, f1);
        float4 as0 = *(const float4*)(att_src + c * 8);
        float4 as1 = *(const float4*)(att_src + c * 8 + 4);
        float4 as2 = *(const float4*)(att_src + 128 + c * 8);
        float4 as3 = *(const float4*)(att_src + 128 + c * 8 + 4);
        float4 ad0 = *(const float4*)(att_dst + c * 8);
        float4 ad1 = *(const float4*)(att_dst + c * 8 + 4);
        float4 ad2 = *(const float4*)(att_dst + 128 + c * 8);
        float4 ad3 = *(const float4*)(att_dst + 128 + c * 8 + 4);

        float ps0 = f0[0]*as0.x + f0[1]*as0.y + f0[2]*as0.z + f0[3]*as0.w
                  + f0[4]*as1.x + f0[5]*as1.y + f0[6]*as1.z + f0[7]*as1.w;
        float pd0 = f0[0]*ad0.x + f0[1]*ad0.y + f0[2]*ad0.z + f0[3]*ad0.w
                  + f0[4]*ad1.x + f0[5]*ad1.y + f0[6]*ad1.z + f0[7]*ad1.w;
        float ps1 = f1[0]*as2.x + f1[1]*as2.y + f1[2]*as2.z + f1[3]*as2.w
                  + f1[4]*as3.x + f1[5]*as3.y + f1[6]*as3.z + f1[7]*as3.w;
        float pd1 = f1[0]*ad2.x + f1[1]*ad2.y + f1[2]*ad2.z + f1[3]*ad2.w
                  + f1[4]*ad3.x + f1[5]*ad3.y + f1[6]*ad3.z + f1[7]*ad3.w;

        // reduce the 4 groups of one head (c&3) -> full 32-col dot
        ps0 += __shfl_xor(ps0, 1, 64); ps0 += __shfl_xor(ps0, 2, 64);
        ps1 += __shfl_xor(ps1, 1, 64); ps1 += __shfl_xor(ps1, 2, 64);
        pd0 += __shfl_xor(pd0, 1, 64); pd0 += __shfl_xor(pd0, 2, 64);
        pd1 += __shfl_xor(pd1, 1, 64); pd1 += __shfl_xor(pd1, 2, 64);
        if ((c & 3) == 0) {
            int node = nb + row;
            int h = c >> 2;
            a_src[node * 8 + h]     = ps0;
            a_src[node * 8 + 4 + h] = ps1;
            a_dst[node * 8 + h]     = pd0;
            a_dst[node * 8 + 4 + h] = pd1;
        }
    }
}

// ---- CSR build: hist + 3-kernel parallel scan + scatter ----
__global__ void k_hist(const int* __restrict__ dst, int* __restrict__ deg, int E) {
    int e = blockIdx.x * 256 + threadIdx.x;
    if (e < E) atomicAdd(&deg[dst[e]], 1);
}

__global__ __launch_bounds__(256) void k_scan1(const int* __restrict__ deg, int* __restrict__ bsum) {
    __shared__ int sm[256];
    int tid = threadIdx.x;
    int i = blockIdx.x * 256 + tid;
    int v = (i < N_NODES) ? deg[i] : 0;
    sm[tid] = v;
    __syncthreads();
#pragma unroll
    for (int o = 128; o > 0; o >>= 1) {
        if (tid < o) sm[tid] += sm[tid + o];
        __syncthreads();
    }
    if (tid == 0) bsum[blockIdx.x] = sm[0];
}

__global__ __launch_bounds__(256) void k_scan2(int* __restrict__ bsum, int* __restrict__ off) {
    __shared__ int sm[256];
    int tid = threadIdx.x;
    int v = (tid < SCAN_B) ? bsum[tid] : 0;
    sm[tid] = v;
    __syncthreads();
#pragma unroll
    for (int o = 1; o < 256; o <<= 1) {
        int t = (tid >= o) ? sm[tid - o] : 0;
        __syncthreads();
        sm[tid] += t;
        __syncthreads();
    }
    bsum[tid] = sm[tid] - v;                 // exclusive
    if (tid == 255) off[N_NODES] = sm[255];  // total
}

__global__ __launch_bounds__(256) void k_scan3(const int* __restrict__ deg,
                                               const int* __restrict__ bsum,
                                               int* __restrict__ off, int* __restrict__ cur) {
    __shared__ int sm[256];
    int tid = threadIdx.x;
    int i = blockIdx.x * 256 + tid;
    int v = (i < N_NODES) ? deg[i] : 0;
    sm[tid] = v;
    __syncthreads();
#pragma unroll
    for (int o = 1; o < 256; o <<= 1) {
        int t = (tid >= o) ? sm[tid - o] : 0;
        __syncthreads();
        sm[tid] += t;
        __syncthreads();
    }
    if (i < N_NODES) {
        int excl = sm[tid] - v + bsum[blockIdx.x];
        off[i] = excl;
        cur[i] = excl;
    }
}

__global__ void k_scatter(const int* __restrict__ src, const int* __restrict__ dst,
                          int* __restrict__ cur, int* __restrict__ csr, int E) {
    int e = blockIdx.x * 256 + threadIdx.x;
    if (e < E) {
        int pos = atomicAdd(&cur[dst[e]], 1);
        csr[pos] = src[e];
    }
}

// ---- aggregation: one wave per destination, unroll-by-2; fp16 payload ----
__global__ __launch_bounds__(256) void k_agg(const uint16_t* __restrict__ xwh,
                                             const float* __restrict__ a_src,
                                             const float* __restrict__ a_dst,
                                             const int* __restrict__ off,
                                             const int* __restrict__ csr,
                                             const float* __restrict__ bias,
                                             float* __restrict__ out) {
    int i    = blockIdx.x * 4 + (threadIdx.x >> 6);
    int lane = threadIdx.x & 63;
    if (i >= N_NODES) return;
    int h = lane >> 3;
    float sdst = a_dst[i * 8 + h];

    float s0 = a_src[i * 8 + h] + sdst;
    s0 = (s0 > 0.f) ? s0 : 0.2f * s0;
    float p0 = __expf(s0);
    float l = p0;
    uint2 us = *(const uint2*)(xwh + (size_t)i * HC + lane * 4);
    float sx0, sx1, sx2, sx3;
    ld4h(us, sx0, sx1, sx2, sx3);
    float a0 = p0 * sx0, a1 = p0 * sx1, a2 = p0 * sx2, a3 = p0 * sx3;

    int start = off[i], end = off[i + 1];
    for (int base = start; base < end; base += 64) {
        int nb = min(64, end - base);
        int myj = (base + lane < end) ? csr[base + lane] : 0;
        int t = 0;
        for (; t + 1 < nb; t += 2) {
            int j0 = __shfl(myj, t, 64);
            int j1 = __shfl(myj, t + 1, 64);
            float sa0 = a_src[j0 * 8 + h];
            float sa1 = a_src[j1 * 8 + h];
            uint2 u0 = *(const uint2*)(xwh + (size_t)j0 * HC + lane * 4);
            uint2 u1 = *(const uint2*)(xwh + (size_t)j1 * HC + lane * 4);
            float sA = sa0 + sdst; sA = (sA > 0.f) ? sA : 0.2f * sA;
            float sB = sa1 + sdst; sB = (sB > 0.f) ? sB : 0.2f * sB;
            float pA = __expf(sA);
            float pB = __expf(sB);
            l += pA + pB;
            float f0, f1, f2, f3, g0, g1, g2, g3;
            ld4h(u0, f0, f1, f2, f3);
            ld4h(u1, g0, g1, g2, g3);
            a0 = fmaf(pA, f0, a0); a1 = fmaf(pA, f1, a1);
            a2 = fmaf(pA, f2, a2); a3 = fmaf(pA, f3, a3);
            a0 = fmaf(pB, g0, a0); a1 = fmaf(pB, g1, a1);
            a2 = fmaf(pB, g2, a2); a3 = fmaf(pB, g3, a3);
        }
        if (t < nb) {
            int j = __shfl(myj, t, 64);
            float s = a_src[j * 8 + h] + sdst;
            s = (s > 0.f) ? s : 0.2f * s;
            float p = __expf(s);
            l += p;
            uint2 u = *(const uint2*)(xwh + (size_t)j * HC + lane * 4);
            float f0, f1, f2, f3;
            ld4h(u, f0, f1, f2, f3);
            a0 = fmaf(p, f0, a0); a1 = fmaf(p, f1, a1);
            a2 = fmaf(p, f2, a2); a3 = fmaf(p, f3, a3);
        }
    }
    float inv = 1.f / (l + 1e-16f);
    float4 b = *(const float4*)(bias + lane * 4);
    float4 o;
    o.x = fmaf(a0, inv, b.x);
    o.y = fmaf(a1, inv, b.y);
    o.z = fmaf(a2, inv, b.z);
    o.w = fmaf(a3, inv, b.w);
    *(float4*)(out + (size_t)i * HC + lane * 4) = o;
}

extern "C" void kernel_launch(void* const* d_in, const int* in_sizes, int n_in,
                              void* d_out, int out_size, void* d_ws, size_t ws_size,
                              hipStream_t stream) {
    const float* x       = (const float*)d_in[0];
    const int*   ei      = (const int*)d_in[1];
    const float* W       = (const float*)d_in[2];
    const float* att_src = (const float*)d_in[3];
    const float* att_dst = (const float*)d_in[4];
    const float* bias    = (const float*)d_in[5];
    float*       out     = (float*)d_out;

    const int E = in_sizes[1] / 2;
    const int* src = ei;        // (2,E) int32 row-major — verified r9
    const int* dst = ei + E;

    char* ws = (char*)d_ws;
    uint16_t* xwh   = (uint16_t*)(ws);                         // 25,600,000 B
    uint16_t* Wt    = (uint16_t*)(ws + 25600000);              //     65,536 B
    float*    a_src = (float*)   (ws + 25665536);              //  1,600,000 B
    float*    a_dst = (float*)   (ws + 27265536);              //  1,600,000 B
    int*      off   = (int*)     (ws + 28865536);              //    200,004 B
    int*      deg   = (int*)     (ws + 29065540);              //    200,000 B
    int*      cur   = (int*)     (ws + 29265540);              //    200,000 B
    int*      csr   = (int*)     (ws + 29465540);              //  2,000,000 B
    int*      bsum  = (int*)     (ws + 31465540);              //      1,024 B

    k_wt<<<128, 256, 0, stream>>>(W, Wt);
    k_gemm_fused<<<3125, 256, 0, stream>>>(x, Wt, att_src, att_dst, xwh, a_src, a_dst);
    hipMemsetAsync(deg, 0, N_NODES * sizeof(int), stream);
    k_hist<<<(E + 255) / 256, 256, 0, stream>>>(dst, deg, E);
    k_scan1<<<SCAN_B, 256, 0, stream>>>(deg, bsum);
    k_scan2<<<1, 256, 0, stream>>>(bsum, off);
    k_scan3<<<SCAN_B, 256, 0, stream>>>(deg, bsum, off, cur);
    k_scatter<<<(E + 255) / 256, 256, 0, stream>>>(src, dst, cur, csr, E);
    k_agg<<<12500, 256, 0, stream>>>(xwh, a_src, a_dst, off, csr, bias, out);
}